// Round 6
// baseline (122.081 us; speedup 1.0000x reference)
//
#include <hip/hip_runtime.h>

#define DTF (1.0f/120.0f)

constexpr int Bn = 2048;
constexpr int Tn = 2048;
constexpr int NS = Tn - 1;            // 2047 scan steps
constexpr int ZF = Tn * 3;            // 6144 floats per trajectory
constexpr int RIC_CAP = 256;
constexpr int TAB_ROWS = 2080;        // full-length gain table (tail = converged row)
constexpr int NCH = 64;               // time chunks
constexpr int LCH = 32;               // owned steps per chunk
constexpr int SPAN = 109;             // nominal span -> warm-up 77..80 after alignment
constexpr int NSEG = 14;              // 14*8 = 112 >= SPAN+3
constexpr int BT = 64;                // one wave per block = 64 trajectories
constexpr int GX = Bn / BT;           // 32
constexpr int NBLK = GX * NCH;        // 2048

// ws layout (bytes)
constexpr int WS_CNT  = 0;                            // uint32 completion counter (reset by riccati)
constexpr int WS_STOP = 8;
constexpr int WS_TAB  = 64;                           // TAB_ROWS x 8 floats
constexpr int WS_PART = WS_TAB + TAB_ROWS * 8 * 4;    // NBLK doubles

// ---- Riccati: two exact 2x2 blocks; serial head, converged fill; resets counter ----
__global__ void riccati_kernel(const float* __restrict__ params, char* __restrict__ ws)
{
    __shared__ int s_stop;
    __shared__ float s_conv[8];
    float* tab = (float*)(ws + WS_TAB);
    if (threadIdx.x == 0) {
        *(unsigned*)(ws + WS_CNT) = 0u;            // deterministic counter init every launch
        const float dt = DTF;
        const float damping = params[1];
        const float a = 1.f - dt * damping;
        const float qp = 2e-10f, qv = 3e-7f, qth = 1e-2f, qdth = 1e-1f;
        const float Rp = 2.5e-7f, Rt = 9.1e-3f;
        float x00 = 0.01f, x01 = 0.f, x11 = 0.01f;   // pos/vel block (x == y)
        float t00 = 0.01f, t01 = 0.f, t11 = 0.01f;   // theta block
        int stop = RIC_CAP - 1;
        for (int t = 0; t < RIC_CAP; ++t) {
            float Pp00 = x00 + 2.f*dt*x01 + dt*dt*x11 + qp;
            float Pp01 = a * (x01 + dt*x11);
            float Pp11 = a*a*x11 + qv;
            float Sx = Pp00 + Rp, isx = __builtin_amdgcn_rcpf(Sx);
            float kx0 = Pp00*isx, kx1 = Pp01*isx;
            float nx00 = Pp00 - kx0*Pp00, nx01 = Pp01 - kx0*Pp01, nx11 = Pp11 - kx1*Pp01;
            float Tp00 = t00 + 2.f*dt*t01 + dt*dt*t11 + qth;
            float Tp01 = t01 + dt*t11;
            float Tp11 = t11 + qdth;
            float St = Tp00 + Rt, ist = __builtin_amdgcn_rcpf(St);
            float kt0 = Tp00*ist, kt1 = Tp01*ist;
            float nt00 = Tp00 - kt0*Tp00, nt01 = Tp01 - kt0*Tp01, nt11 = Tp11 - kt1*Tp01;
            float* row = tab + (size_t)t * 8;
            row[0]=kx0; row[1]=kx1; row[2]=kt0; row[3]=kt1;
            row[4]=isx; row[5]=ist; row[6]=Sx*Sx*St; row[7]=0.f;
            float md = fmaxf(fmaxf(fabsf(nx00-x00), fabsf(nx01-x01)), fabsf(nx11-x11));
            md = fmaxf(md, fmaxf(fmaxf(fabsf(nt00-t00), fabsf(nt01-t01)), fabsf(nt11-t11)));
            float mp = fmaxf(fmaxf(fabsf(nx00), fabsf(nx11)), fmaxf(fabsf(nt00), fabsf(nt11)));
            x00=nx00; x01=nx01; x11=nx11; t00=nt00; t01=nt01; t11=nt11;
            if (t >= 48 && md <= 1e-5f * mp) { stop = t; break; }
        }
        *(int*)(ws + WS_STOP) = stop;
        const float* srow = tab + (size_t)stop * 8;
        #pragma unroll
        for (int i = 0; i < 8; ++i) s_conv[i] = srow[i];
        s_stop = stop;
    }
    __syncthreads();
    const int stop = s_stop;
    float4 cA = make_float4(s_conv[0], s_conv[1], s_conv[2], s_conv[3]);
    float4 cB = make_float4(s_conv[4], s_conv[5], s_conv[6], 0.f);
    for (int r = stop + 1 + threadIdx.x; r < TAB_ROWS; r += blockDim.x) {
        float4* row = (float4*)(tab + (size_t)r * 8);
        row[0] = cA; row[1] = cB;
    }
}

// ---- main filter: 1 wave/block, LDS-transposed coalesced z, fused finalize ----
__global__ __launch_bounds__(BT, 2) void ekf_main(const float* __restrict__ params,
                                                  const float* __restrict__ meas,
                                                  char* __restrict__ ws,
                                                  float* __restrict__ out)
{
    __shared__ float lds[28 * 65];           // [28 slots][65] transposed z window

    const int tid = threadIdx.x;
    const int b0 = blockIdx.x * BT;
    const int c  = blockIdx.y;
    const float dt = DTF;
    const float fric = params[0];
    const float damping = params[1];
    const float a = 1.f - dt * damping;
    const float dfr = dt * fric;
    const float* __restrict__ tab = (const float*)(ws + WS_TAB);
    const float* __restrict__ zt = meas + (size_t)b0 * ZF;   // block's 64 trajectories

    const int j0   = c * LCH;
    const int jend = min(j0 + LCH, NS);
    int jw = jend - SPAN;
    jw = (jw < 3) ? 0 : (jw - ((jw - 3) & 3));   // jw == 3 (mod 4), or 0 (exact head)
    const int A0 = (jw * 3 + 3) & ~3;            // aligned base of step windows
    const int d  = jw * 3 + 3 - A0;              // 0..3, uniform
    const int AI = (jw * 3) & ~3;                // aligned base of init window
    const int di = jw * 3 - AI;                  // 0..3, uniform

    // coalesced frame staging: 7 x float4/thread covers 64 rows x 28 floats
    float4 g[7];
#define LOADF(A) do { \
    _Pragma("unroll") \
    for (int i_ = 0; i_ < 7; ++i_) { \
        int flat_ = i_ * BT + tid; \
        int row_ = flat_ / 7, k_ = flat_ - row_ * 7; \
        int fs_ = min((A) + 4 * k_, ZF - 4); \
        g[i_] = *(const float4*)(zt + (size_t)row_ * ZF + fs_); \
    } \
} while (0)
#define STORELDS() do { \
    _Pragma("unroll") \
    for (int i_ = 0; i_ < 7; ++i_) { \
        int flat_ = i_ * BT + tid; \
        int row_ = flat_ / 7, k_ = flat_ - row_ * 7; \
        int base_ = 4 * k_ * 65 + row_; \
        lds[base_]       = g[i_].x; \
        lds[base_ + 65]  = g[i_].y; \
        lds[base_ + 130] = g[i_].z; \
        lds[base_ + 195] = g[i_].w; \
    } \
} while (0)

    // init window: z[jw], z[jw+1] via the same coalesced/transpose path
    LOADF(AI);
    STORELDS();
    float i0 = lds[(di+0)*65 + tid], i1 = lds[(di+1)*65 + tid], i2 = lds[(di+2)*65 + tid];
    float i3 = lds[(di+3)*65 + tid], i4 = lds[(di+4)*65 + tid], i5 = lds[(di+5)*65 + tid];
    float s0 = i0, s1 = i1, s4 = i2;
    float s2 = (i3 - i0) / dt, s3 = (i4 - i1) / dt, s5 = (i5 - i2) / dt;

    LOADF(A0);                                   // frame 0 in flight
    float facc = 0.f;
    for (int s = 0; s < NSEG; ++s) {
        const int jb = jw + 8 * s;
        STORELDS();                              // frame s -> LDS (in-order DS queue)
        if (s + 1 < NSEG) LOADF(A0 + 24 * (s + 1));   // issue next frame early
        float zv[24];
        #pragma unroll
        for (int k2 = 0; k2 < 24; ++k2) zv[k2] = lds[(d + k2) * 65 + tid];
        const float* trow = tab + (size_t)jb * 8;     // wave-uniform -> scalar loads
        #pragma unroll
        for (int ss = 0; ss < 8; ++ss) {
            float kx0 = trow[ss*8+0], kx1 = trow[ss*8+1];
            float kt0 = trow[ss*8+2], kt1 = trow[ss*8+3];
            float isx = trow[ss*8+4], ist = trow[ss*8+5], det = trow[ss*8+6];
            float p0 = fmaf(dt, s2, s0), p1 = fmaf(dt, s3, s1), p4 = fmaf(dt, s5, s4);
            float p2 = fmaf(a, s2, -copysignf(dfr, s2));
            float p3 = fmaf(a, s3, -copysignf(dfr, s3));
            float y0 = zv[ss*3+0] - p0, y1 = zv[ss*3+1] - p1, y2 = zv[ss*3+2] - p4;
            s0 = fmaf(kx0, y0, p0); s1 = fmaf(kx0, y1, p1);
            s2 = fmaf(kx1, y0, p2); s3 = fmaf(kx1, y1, p3);
            s4 = fmaf(kt0, y2, p4); s5 = fmaf(kt1, y2, s5);
            int j = jb + ss;
            if (j >= j0 && j < jend)
                facc += det + isx * fmaf(y0, y0, y1 * y1) + ist * y2 * y2;
        }
    }
#undef STORELDS
#undef LOADF

    // wave reduce -> device-scope partial; last block (counter reset each launch) finalizes
    double acc = (double)facc;
    for (int off = 32; off; off >>= 1) acc += __shfl_down(acc, off);
    unsigned long long* part = (unsigned long long*)(ws + WS_PART);
    unsigned* cnt = (unsigned*)(ws + WS_CNT);
    unsigned old = 0;
    if (tid == 0) {
        atomicExch(&part[blockIdx.y * GX + blockIdx.x],
                   (unsigned long long)__double_as_longlong(acc));
        __threadfence();
        old = atomicAdd(cnt, 1u);
    }
    old = __shfl(old, 0);
    if (old == (unsigned)(NBLK - 1)) {
        __threadfence();
        double v = 0.0;
        #pragma unroll
        for (int i = 0; i < NBLK / BT; ++i) {
            unsigned long long bits = atomicAdd(&part[i * BT + tid], 0ULL);
            v += __longlong_as_double((long long)bits);
        }
        for (int off = 32; off; off >>= 1) v += __shfl_down(v, off);
        if (tid == 0) out[0] = (float)(v / ((double)Bn * (double)NS));
    }
}

extern "C" void kernel_launch(void* const* d_in, const int* in_sizes, int n_in,
                              void* d_out, int out_size, void* d_ws, size_t ws_size,
                              hipStream_t stream)
{
    const float* params = (const float*)d_in[0];
    const float* meas = (const float*)d_in[1];
    char* ws = (char*)d_ws;
    float* out = (float*)d_out;

    hipLaunchKernelGGL(riccati_kernel, dim3(1), dim3(256), 0, stream, params, ws);
    hipLaunchKernelGGL(ekf_main, dim3(GX, NCH), dim3(BT), 0, stream, params, meas, ws, out);
}

// Round 7
// 121.738 us; speedup vs baseline: 1.0028x; 1.0028x over previous
//
#include <hip/hip_runtime.h>

#define DTF (1.0f/120.0f)

constexpr int Bn = 2048;
constexpr int Tn = 2048;
constexpr int NS = Tn - 1;            // 2047 scan steps
constexpr int ZF = Tn * 3;            // 6144 floats per trajectory
constexpr int RIC_CAP = 256;
constexpr int TAB_ROWS = 512;         // head chunks read rows < stop+120 <= 375
constexpr int NCH = 64;               // time chunks
constexpr int LCH = 32;               // owned steps per chunk
constexpr int SPAN = 109;             // warm-up 77 after alignment
constexpr int NSEG = 14;              // 14*8 = 112 steps executed
constexpr int BT = 64;                // one wave per block
constexpr int GX = Bn / BT;           // 32
constexpr int NBLK = GX * NCH;        // 2048
constexpr int LSTR = 66;              // LDS slot stride (write conflicts -> free 2-way)

// ws layout (bytes)
constexpr int WS_CNT  = 0;            // uint32 completion counter (reset each launch)
constexpr int WS_STOP = 8;
constexpr int WS_CONV = 16;           // 8 floats converged row
constexpr int WS_TAB  = 64;           // TAB_ROWS x 8 floats
constexpr int WS_PART = WS_TAB + TAB_ROWS * 8 * 4;   // NBLK doubles

// ---- Riccati: two exact 2x2 blocks; serial head, converged fill; resets counter ----
__global__ void riccati_kernel(const float* __restrict__ params, char* __restrict__ ws)
{
    __shared__ int s_stop;
    __shared__ float s_conv[8];
    float* tab = (float*)(ws + WS_TAB);
    if (threadIdx.x == 0) {
        *(unsigned*)(ws + WS_CNT) = 0u;            // deterministic counter init every launch
        const float dt = DTF;
        const float damping = params[1];
        const float a = 1.f - dt * damping;
        const float qp = 2e-10f, qv = 3e-7f, qth = 1e-2f, qdth = 1e-1f;
        const float Rp = 2.5e-7f, Rt = 9.1e-3f;
        float x00 = 0.01f, x01 = 0.f, x11 = 0.01f;   // pos/vel block (x == y)
        float t00 = 0.01f, t01 = 0.f, t11 = 0.01f;   // theta block
        int stop = RIC_CAP - 1;
        for (int t = 0; t < RIC_CAP; ++t) {
            float Pp00 = x00 + 2.f*dt*x01 + dt*dt*x11 + qp;
            float Pp01 = a * (x01 + dt*x11);
            float Pp11 = a*a*x11 + qv;
            float Sx = Pp00 + Rp, isx = __builtin_amdgcn_rcpf(Sx);
            float kx0 = Pp00*isx, kx1 = Pp01*isx;
            float nx00 = Pp00 - kx0*Pp00, nx01 = Pp01 - kx0*Pp01, nx11 = Pp11 - kx1*Pp01;
            float Tp00 = t00 + 2.f*dt*t01 + dt*dt*t11 + qth;
            float Tp01 = t01 + dt*t11;
            float Tp11 = t11 + qdth;
            float St = Tp00 + Rt, ist = __builtin_amdgcn_rcpf(St);
            float kt0 = Tp00*ist, kt1 = Tp01*ist;
            float nt00 = Tp00 - kt0*Tp00, nt01 = Tp01 - kt0*Tp01, nt11 = Tp11 - kt1*Tp01;
            float* row = tab + (size_t)t * 8;
            row[0]=kx0; row[1]=kx1; row[2]=kt0; row[3]=kt1;
            row[4]=isx; row[5]=ist; row[6]=Sx*Sx*St; row[7]=0.f;
            float md = fmaxf(fmaxf(fabsf(nx00-x00), fabsf(nx01-x01)), fabsf(nx11-x11));
            md = fmaxf(md, fmaxf(fmaxf(fabsf(nt00-t00), fabsf(nt01-t01)), fabsf(nt11-t11)));
            float mp = fmaxf(fmaxf(fabsf(nx00), fabsf(nx11)), fmaxf(fabsf(nt00), fabsf(nt11)));
            x00=nx00; x01=nx01; x11=nx11; t00=nt00; t01=nt01; t11=nt11;
            if (t >= 48 && md <= 1e-5f * mp) { stop = t; break; }
        }
        *(int*)(ws + WS_STOP) = stop;
        const float* srow = tab + (size_t)stop * 8;
        float* cv = (float*)(ws + WS_CONV);
        #pragma unroll
        for (int i = 0; i < 8; ++i) { s_conv[i] = srow[i]; cv[i] = srow[i]; }
        s_stop = stop;
    }
    __syncthreads();
    const int stop = s_stop;
    float4 cA = make_float4(s_conv[0], s_conv[1], s_conv[2], s_conv[3]);
    float4 cB = make_float4(s_conv[4], s_conv[5], s_conv[6], 0.f);
    for (int r = stop + 1 + threadIdx.x; r < TAB_ROWS; r += blockDim.x) {
        float4* row = (float4*)(tab + (size_t)r * 8);
        row[0] = cA; row[1] = cB;
    }
}

// ---- main filter: 1 wave/block, coalesced LDS-transposed z, reg/LDS gains ----
__global__ __launch_bounds__(BT, 4) void ekf_main(const float* __restrict__ params,
                                                  const float* __restrict__ meas,
                                                  char* __restrict__ ws,
                                                  float* __restrict__ out)
{
    __shared__ float lds[28 * LSTR];       // transposed z window [28 slots][66]
    __shared__ float sh_tab[120 * 8];      // head-path gain rows (LDS broadcast reads)

    const int tid = threadIdx.x;
    const int b0 = blockIdx.x * BT;
    const int c  = blockIdx.y;
    const float dt = DTF;
    const float fric = params[0];
    const float damping = params[1];
    const float a = 1.f - dt * damping;
    const float dfr = dt * fric;
    const float* __restrict__ tabg = (const float*)(ws + WS_TAB);
    const float* __restrict__ zt = meas + (size_t)b0 * ZF;   // block's 64 trajectories

    const int j0   = c * LCH;
    const int jend = min(j0 + LCH, NS);
    int jw = jend - SPAN;
    jw = (jw < 3) ? 0 : (jw - ((jw - 3) & 3));   // jw == 3 (mod 4), or 0 (exact head)
    const int A0 = (jw * 3 + 3) & ~3;            // aligned base of step windows (d==0 unless jw==0)
    const int d  = jw * 3 + 3 - A0;
    const int AI = (jw * 3) & ~3;                // aligned base of init window
    const int di = jw * 3 - AI;

    float4 g[7];
#define LOADF(A) do { \
    _Pragma("unroll") \
    for (int i_ = 0; i_ < 7; ++i_) { \
        int flat_ = i_ * BT + tid; \
        int row_ = flat_ / 7, k_ = flat_ - row_ * 7; \
        int fs_ = min((A) + 4 * k_, ZF - 4); \
        g[i_] = *(const float4*)(zt + (size_t)row_ * ZF + fs_); \
    } \
} while (0)
#define STORELDS() do { \
    _Pragma("unroll") \
    for (int i_ = 0; i_ < 7; ++i_) { \
        int flat_ = i_ * BT + tid; \
        int row_ = flat_ / 7, k_ = flat_ - row_ * 7; \
        int base_ = 4 * k_ * LSTR + row_; \
        lds[base_]            = g[i_].x; \
        lds[base_ + LSTR]     = g[i_].y; \
        lds[base_ + 2*LSTR]   = g[i_].z; \
        lds[base_ + 3*LSTR]   = g[i_].w; \
    } \
} while (0)

    LOADF(AI);                                   // init window in flight first

    const int stop = *(const int*)(ws + WS_STOP);
    const bool conv = (jw > stop);
    const float* __restrict__ cvv = (const float*)(ws + WS_CONV);
    const float ckx0=cvv[0], ckx1=cvv[1], ckt0=cvv[2], ckt1=cvv[3];
    const float cisx=cvv[4], cist=cvv[5], cdet=cvv[6];
    if (!conv) {
        #pragma unroll
        for (int i = 0; i < 15; ++i)             // rows jw..jw+119, coalesced
            sh_tab[i * BT + tid] = tabg[(size_t)jw * 8 + i * BT + tid];
    }

    STORELDS();
    float i0 = lds[(di+0)*LSTR + tid], i1 = lds[(di+1)*LSTR + tid], i2 = lds[(di+2)*LSTR + tid];
    float i3 = lds[(di+3)*LSTR + tid], i4 = lds[(di+4)*LSTR + tid], i5 = lds[(di+5)*LSTR + tid];
    float s0 = i0, s1 = i1, s4 = i2;
    float s2 = (i3 - i0) / dt, s3 = (i4 - i1) / dt, s5 = (i5 - i2) / dt;

    LOADF(A0);
    float facc = 0.f;

#define SEG_PRE(S) \
    const int jb = jw + 8 * (S); \
    STORELDS(); \
    if ((S) + 1 < NSEG) LOADF(A0 + 24 * ((S) + 1)); \
    float zv[24]; \
    _Pragma("unroll") \
    for (int k2 = 0; k2 < 24; ++k2) zv[k2] = lds[(d + k2) * LSTR + tid];

#define STEP_BODY(KX0,KX1,KT0,KT1,ISX,IST,DET) \
    float p0 = fmaf(dt, s2, s0), p1 = fmaf(dt, s3, s1), p4 = fmaf(dt, s5, s4); \
    float p2 = fmaf(a, s2, -copysignf(dfr, s2)); \
    float p3 = fmaf(a, s3, -copysignf(dfr, s3)); \
    float y0 = zv[ss*3+0] - p0, y1 = zv[ss*3+1] - p1, y2 = zv[ss*3+2] - p4; \
    s0 = fmaf(KX0, y0, p0); s1 = fmaf(KX0, y1, p1); \
    s2 = fmaf(KX1, y0, p2); s3 = fmaf(KX1, y1, p3); \
    s4 = fmaf(KT0, y2, p4); s5 = fmaf(KT1, y2, s5); \
    int j = jb + ss; \
    if (j >= j0 && j < jend) \
        facc += DET + ISX * fmaf(y0, y0, y1 * y1) + IST * y2 * y2;

    if (conv) {
        #pragma unroll
        for (int s = 0; s < NSEG; ++s) {
            SEG_PRE(s)
            #pragma unroll
            for (int ss = 0; ss < 8; ++ss) {
                STEP_BODY(ckx0, ckx1, ckt0, ckt1, cisx, cist, cdet)
            }
        }
    } else {
        #pragma unroll
        for (int s = 0; s < NSEG; ++s) {
            SEG_PRE(s)
            #pragma unroll
            for (int ss = 0; ss < 8; ++ss) {
                const float* tr = sh_tab + (size_t)(8 * s + ss) * 8;   // LDS broadcast
                STEP_BODY(tr[0], tr[1], tr[2], tr[3], tr[4], tr[5], tr[6])
            }
        }
    }
#undef STEP_BODY
#undef SEG_PRE
#undef STORELDS
#undef LOADF

    // wave reduce -> device-scope partial; last block finalizes (counter reset each launch)
    double acc = (double)facc;
    for (int off = 32; off; off >>= 1) acc += __shfl_down(acc, off);
    unsigned long long* part = (unsigned long long*)(ws + WS_PART);
    unsigned* cnt = (unsigned*)(ws + WS_CNT);
    unsigned old = 0;
    if (tid == 0) {
        atomicExch(&part[blockIdx.y * GX + blockIdx.x],
                   (unsigned long long)__double_as_longlong(acc));
        __threadfence();
        old = atomicAdd(cnt, 1u);
    }
    old = __shfl(old, 0);
    if (old == (unsigned)(NBLK - 1)) {
        __threadfence();
        double v = 0.0;
        #pragma unroll
        for (int i = 0; i < NBLK / BT; ++i) {
            unsigned long long bits = atomicAdd(&part[i * BT + tid], 0ULL);
            v += __longlong_as_double((long long)bits);
        }
        for (int off = 32; off; off >>= 1) v += __shfl_down(v, off);
        if (tid == 0) out[0] = (float)(v / ((double)Bn * (double)NS));
    }
}

extern "C" void kernel_launch(void* const* d_in, const int* in_sizes, int n_in,
                              void* d_out, int out_size, void* d_ws, size_t ws_size,
                              hipStream_t stream)
{
    const float* params = (const float*)d_in[0];
    const float* meas = (const float*)d_in[1];
    char* ws = (char*)d_ws;
    float* out = (float*)d_out;

    hipLaunchKernelGGL(riccati_kernel, dim3(1), dim3(256), 0, stream, params, ws);
    hipLaunchKernelGGL(ekf_main, dim3(GX, NCH), dim3(BT), 0, stream, params, meas, ws, out);
}

// Round 8
// 39.336 us; speedup vs baseline: 3.1035x; 3.0948x over previous
//
#include <hip/hip_runtime.h>

#define DTF (1.0f/120.0f)

constexpr int Bn = 2048;
constexpr int Tn = 2048;
constexpr int NS = Tn - 1;            // 2047 scan steps
constexpr int ZF = Tn * 3;            // 6144 floats per trajectory
constexpr int NCH = 64;               // time chunks
constexpr int LCH = 32;               // owned steps per chunk
constexpr int SPAN = 109;             // warm-up >= 77 after alignment
constexpr int NSEG = 14;              // 14*8 = 112 executed steps
constexpr int BT = 64;                // one wave per block
constexpr int GX = Bn / BT;           // 32
constexpr int NBLK = GX * NCH;        // 2048 partials
constexpr int LSTR = 66;              // LDS slot stride

// ---- main filter: fused per-step 2x2 Riccati + filter; no tables, no atomics ----
__global__ __launch_bounds__(BT, 2) void ekf_main(const float* __restrict__ params,
                                                  const float* __restrict__ meas,
                                                  double* __restrict__ part)
{
    __shared__ float lds[28 * LSTR];         // transposed z window [28 slots][66]

    const int tid = threadIdx.x;
    const int c = blockIdx.y;
    const float dt = DTF;
    const float fric = params[0];
    const float damping = params[1];
    const float a = 1.f - dt * damping;
    const float dfr = dt * fric;
    const float dt2 = dt * dt, a2 = a * a;
    const float qp = 2e-10f, qv = 3e-7f, qth = 1e-2f, qdth = 1e-1f;
    const float Rp = 2.5e-7f, Rt = 9.1e-3f;
    const float* __restrict__ zt = meas + (size_t)(blockIdx.x * BT) * ZF;

    const int j0   = c * LCH;
    const int jend = min(j0 + LCH, NS);
    int jw = jend - SPAN;
    jw = (jw < 3) ? 0 : (jw - ((jw - 3) & 3));   // jw % 4 == 3, or 0 (exact head)
    const int A0 = (jw * 3 + 3) & ~3;            // aligned base of step windows
    const int d  = jw * 3 + 3 - A0;              // 0..3 uniform
    const int AI = (jw * 3) & ~3;                // aligned base of init window
    const int di = jw * 3 - AI;

    float4 g[7];
#define LOADF(A) do { \
    _Pragma("unroll") \
    for (int i_ = 0; i_ < 7; ++i_) { \
        int flat_ = i_ * BT + tid; \
        int row_ = flat_ / 7, k_ = flat_ - row_ * 7; \
        int fs_ = min((A) + 4 * k_, ZF - 4); \
        g[i_] = *(const float4*)(zt + (size_t)row_ * ZF + fs_); \
    } \
} while (0)
#define STORELDS() do { \
    _Pragma("unroll") \
    for (int i_ = 0; i_ < 7; ++i_) { \
        int flat_ = i_ * BT + tid; \
        int row_ = flat_ / 7, k_ = flat_ - row_ * 7; \
        int base_ = 4 * k_ * LSTR + row_; \
        lds[base_]            = g[i_].x; \
        lds[base_ + LSTR]     = g[i_].y; \
        lds[base_ + 2*LSTR]   = g[i_].z; \
        lds[base_ + 3*LSTR]   = g[i_].w; \
    } \
} while (0)

    // init window via the coalesced/transpose path (no divergent gathers)
    LOADF(AI);
    STORELDS();
    float i0 = lds[(di+0)*LSTR + tid], i1 = lds[(di+1)*LSTR + tid], i2 = lds[(di+2)*LSTR + tid];
    float i3 = lds[(di+3)*LSTR + tid], i4 = lds[(di+4)*LSTR + tid], i5 = lds[(di+5)*LSTR + tid];
    float s0 = i0, s1 = i1, s4 = i2;
    float s2 = (i3 - i0) / dt, s3 = (i4 - i1) / dt, s5 = (i5 - i2) / dt;

    // covariance blocks warm-start at P0 (exact for jw==0; contracted by >=77 steps otherwise)
    float x00 = 0.01f, x01 = 0.f, x11 = 0.01f;   // pos/vel block (shared by x and y)
    float t00 = 0.01f, t01 = 0.f, t11 = 0.01f;   // theta block

    LOADF(A0);                                   // frame 0 in flight
    float facc = 0.f;

    for (int s = 0; s < NSEG; ++s) {             // rolled: ~3KB code, fits L1I
        STORELDS();                              // frame s -> LDS (in-order DS queue per wave)
        LOADF(A0 + 24 * (s + 1));                // issue next frame early (clamped at tail)
        __builtin_amdgcn_sched_barrier(0);
        float zv[24];
        #pragma unroll
        for (int k2 = 0; k2 < 24; ++k2) zv[k2] = lds[(d + k2) * LSTR + tid];
        const int jb = jw + 8 * s;
        #pragma unroll
        for (int ss = 0; ss < 8; ++ss) {
            // ---- Riccati step (gain for this step from current P) ----
            float Pp00 = fmaf(dt2, x11, fmaf(2.f * dt, x01, x00)) + qp;
            float Pp01 = a * fmaf(dt, x11, x01);
            float Pp11 = fmaf(a2, x11, qv);
            float Sx = Pp00 + Rp;
            float isx = __builtin_amdgcn_rcpf(Sx);
            float kx0 = Pp00 * isx, kx1 = Pp01 * isx;
            x00 = Pp00 - kx0 * Pp00; x01 = Pp01 - kx0 * Pp01; x11 = Pp11 - kx1 * Pp01;
            float Tp00 = fmaf(dt2, t11, fmaf(2.f * dt, t01, t00)) + qth;
            float Tp01 = fmaf(dt, t11, t01);
            float Tp11 = t11 + qdth;
            float St = Tp00 + Rt;
            float ist = __builtin_amdgcn_rcpf(St);
            float kt0 = Tp00 * ist, kt1 = Tp01 * ist;
            t00 = Tp00 - kt0 * Tp00; t01 = Tp01 - kt0 * Tp01; t11 = Tp11 - kt1 * Tp01;
            float det = Sx * Sx * St;
            // ---- filter step ----
            float p0 = fmaf(dt, s2, s0), p1 = fmaf(dt, s3, s1), p4 = fmaf(dt, s5, s4);
            float p2 = fmaf(a, s2, -copysignf(dfr, s2));
            float p3 = fmaf(a, s3, -copysignf(dfr, s3));
            float y0 = zv[ss*3+0] - p0, y1 = zv[ss*3+1] - p1, y2 = zv[ss*3+2] - p4;
            s0 = fmaf(kx0, y0, p0); s1 = fmaf(kx0, y1, p1);
            s2 = fmaf(kx1, y0, p2); s3 = fmaf(kx1, y1, p3);
            s4 = fmaf(kt0, y2, p4); s5 = fmaf(kt1, y2, s5);
            int j = jb + ss;
            if (j >= j0 && j < jend)
                facc += det + isx * fmaf(y0, y0, y1 * y1) + ist * y2 * y2;
        }
    }
#undef STORELDS
#undef LOADF

    // wave reduce -> plain per-block store (kernel boundary orders visibility)
    double acc = (double)facc;
    for (int off = 32; off; off >>= 1) acc += __shfl_down(acc, off);
    if (tid == 0) part[blockIdx.y * GX + blockIdx.x] = acc;
}

// ---- finalize: reduce 2048 partials, no atomics ----
__global__ void finalize_kernel(const double* __restrict__ part, float* __restrict__ out)
{
    const int tid = threadIdx.x;               // 1024 threads
    double v = part[tid] + part[tid + 1024];
    for (int off = 32; off; off >>= 1) v += __shfl_down(v, off);
    __shared__ double wp[16];
    if ((tid & 63) == 0) wp[tid >> 6] = v;
    __syncthreads();
    if (tid == 0) {
        double t = 0.0;
        #pragma unroll
        for (int i = 0; i < 16; ++i) t += wp[i];
        out[0] = (float)(t / ((double)Bn * (double)NS));
    }
}

extern "C" void kernel_launch(void* const* d_in, const int* in_sizes, int n_in,
                              void* d_out, int out_size, void* d_ws, size_t ws_size,
                              hipStream_t stream)
{
    const float* params = (const float*)d_in[0];
    const float* meas = (const float*)d_in[1];
    double* part = (double*)d_ws;
    float* out = (float*)d_out;

    hipLaunchKernelGGL(ekf_main, dim3(GX, NCH), dim3(BT), 0, stream, params, meas, part);
    hipLaunchKernelGGL(finalize_kernel, dim3(1), dim3(1024), 0, stream, part, out);
}